// Round 5
// baseline (192.717 us; speedup 1.0000x reference)
//
#include <hip/hip_runtime.h>
#include <hip/hip_bf16.h>

// Attention fwd with materialized p_attn.
// B=16, S=2048, D=64, f32 in/out. d_out = [out (B,S,D) | p_attn (B,S,S)] f32.
#define BN 16
#define SN 2048
#define DN 64
#define QB 16             // q rows per block
#define NWAVE 8           // 512 threads
#define KSEG (SN / NWAVE) // 256 keys per wave
#define SROW 2056         // bf16 elems per LDS score row (pad -> 16B-aligned stride)

#define SC_L2E 0.18033688011112042f   // 0.125 * log2(e)
#define BI_L2E 11.541560327111707f    // 8 * log2(e): p~ = 2^(acc*SC - BI) = exp(s - 8)

typedef __attribute__((ext_vector_type(8))) short bf16x8;
typedef __attribute__((ext_vector_type(4))) short bf16x4;
typedef __attribute__((ext_vector_type(4))) float f32x4;
typedef __attribute__((ext_vector_type(4))) int   i32x4;
typedef __attribute__((ext_vector_type(2))) unsigned u32x2;

static __device__ __forceinline__ short f2bf(float f) {
    __hip_bfloat16 h = __float2bfloat16(f);   // hardware RNE cvt
    union { __hip_bfloat16 h; short s; } u; u.h = h;
    return u.s;
}
static __device__ __forceinline__ float bf2f(short s) {
    union { unsigned u; float f; } v; v.u = ((unsigned)(unsigned short)s) << 16;
    return v.f;
}
static __device__ __forceinline__ unsigned pk2(float lo, float hi) {
    return ((unsigned)(unsigned short)f2bf(lo)) |
           (((unsigned)(unsigned short)f2bf(hi)) << 16);
}

// ---- prep: K -> bf16 [B][S][D], V -> bf16 transposed [B][D][S] (both in ws) ----
__global__ __launch_bounds__(256)
void prep_kv(const float* __restrict__ K, const float* __restrict__ V,
             short* __restrict__ Kp, short* __restrict__ Vt)
{
    __shared__ short vt[64][68];              // 64x64 tile, pad 4
    const int b  = blockIdx.x >> 5;           // 32 tiles per batch
    const int s0 = (blockIdx.x & 31) << 6;
    const int tid = threadIdx.x;
    const int sr = tid >> 4;                  // 0..15
    const int dc = (tid & 15) << 2;           // 0,4,...,60
    const float* Kb = K + ((size_t)b * SN + s0) * DN;
    const float* Vb = V + ((size_t)b * SN + s0) * DN;
    short* Kpb = Kp + ((size_t)b * SN + s0) * DN;
    #pragma unroll
    for (int i = 0; i < 4; ++i) {
        const int s = sr + i * 16;
        f32x4 kv = *(const f32x4*)(Kb + (size_t)s * DN + dc);
        f32x4 vv = *(const f32x4*)(Vb + (size_t)s * DN + dc);
        bf16x4 k4, v4;
        #pragma unroll
        for (int j = 0; j < 4; ++j) { k4[j] = f2bf(kv[j]); v4[j] = f2bf(vv[j]); }
        *(bf16x4*)(Kpb + (size_t)s * DN + dc) = k4;
        *(bf16x4*)&vt[s][dc] = v4;
    }
    __syncthreads();
    const int d  = tid >> 2;                  // 0..63
    const int sg = (tid & 3) << 4;            // 0,16,32,48
    short* dst = Vt + ((size_t)b * DN + d) * SN + s0 + sg;
    bf16x8 w0, w1;
    #pragma unroll
    for (int j = 0; j < 8; ++j) { w0[j] = vt[sg + j][d]; w1[j] = vt[sg + 8 + j][d]; }
    *(bf16x8*)dst = w0;
    *(bf16x8*)(dst + 8) = w1;
}

// ---- fused attention: barrier-free main pass, 1-chunk SW pipeline ----
// Swapped QK^T: mfma(K,Q) -> lane holds q=lane&15 fixed, k varying over regs.
// p~ = exp(s-8), no max pass (shift cancels in normalize; masked -> 0).
// PV of chunk kb-32 overlaps QK^T/exp/pack of chunk kb (hides LDS round-trip).
template <int PRE>
__global__ __launch_bounds__(512, 2)
void attn_fused(const float* __restrict__ Q, const float* __restrict__ K,
                const float* __restrict__ V, const int* __restrict__ M,
                const short* __restrict__ Kp, const short* __restrict__ Vt,
                float* __restrict__ out)
{
    __shared__ short sbuf[QB * SROW];         // p~ (bf16 bits); later O reduce
    __shared__ float lred[NWAVE * QB];
    __shared__ float lfin[QB];

    const int tid = threadIdx.x;
    const int wv = tid >> 6, ln = tid & 63;
    const int lq = ln & 15, lg = ln >> 4;

    // XCD-bijective swizzle: XCD x serves logical blocks [256x, 256x+255]
    // -> 2 batches per XCD -> K/V ws reads L2-local (1 MB working set).
    const int lb = ((blockIdx.x & 7) << 8) | (blockIdx.x >> 3);
    const int bb = lb >> 7;                   // batch
    const int q0 = (lb & 127) << 4;           // q-tile base

    const float* Qb = Q + ((size_t)bb * SN + q0) * DN;
    const float* Kb = K + (size_t)bb * SN * DN;
    const float* Vb = V + (size_t)bb * SN * DN;
    const short* Kpb = Kp + (size_t)bb * SN * DN;
    const short* Vtb = Vt + (size_t)bb * DN * SN;
    const int*   Mb = M + (size_t)bb * SN;
    float* out_o = out + ((size_t)bb * SN + q0) * DN;
    float* out_p = out + (size_t)BN * SN * DN + ((size_t)bb * SN + q0) * SN;

    // ---- Q fragment (B-operand of swapped QK^T): Q[col=lq][d=8*lg+j] ----
    bf16x8 qf[2];
    #pragma unroll
    for (int s = 0; s < 2; ++s) {
        const float* src = Qb + lq * DN + s * 32 + lg * 8;
        #pragma unroll
        for (int j = 0; j < 8; ++j) qf[s][j] = f2bf(src[j]);
    }

    const int k0 = wv * KSEG;
    f32x4 oacc[4];
    #pragma unroll
    for (int nt = 0; nt < 4; ++nt) oacc[nt] = (f32x4){0.f, 0.f, 0.f, 0.f};
    float lsum = 0.f;

    // QK^T + exp + pack -> LDS for one 32-k chunk
    auto qkexp = [&](int kb) {
        bf16x8 kf0, kf1, kf2, kf3;
        if constexpr (PRE) {
            const short* kr = Kpb + (size_t)(kb + lq) * DN + lg * 8;
            kf0 = *(const bf16x8*)kr;
            kf1 = *(const bf16x8*)(kr + 32);
            kf2 = *(const bf16x8*)(kr + 16 * DN);
            kf3 = *(const bf16x8*)(kr + 16 * DN + 32);
        } else {
            const float* ks = Kb + (size_t)(kb + lq) * DN + lg * 8;
            #pragma unroll
            for (int j = 0; j < 8; ++j) {
                kf0[j] = f2bf(ks[j]);            kf1[j] = f2bf(ks[32 + j]);
                kf2[j] = f2bf(ks[16 * DN + j]);  kf3[j] = f2bf(ks[16 * DN + 32 + j]);
            }
        }
        const i32x4 mv0 = *(const i32x4*)&Mb[kb + 4 * lg];
        const i32x4 mv1 = *(const i32x4*)&Mb[kb + 16 + 4 * lg];

        f32x4 a0 = {0.f, 0.f, 0.f, 0.f}, a1 = {0.f, 0.f, 0.f, 0.f};
        a0 = __builtin_amdgcn_mfma_f32_16x16x32_bf16(kf0, qf[0], a0, 0, 0, 0);
        a0 = __builtin_amdgcn_mfma_f32_16x16x32_bf16(kf1, qf[1], a0, 0, 0, 0);
        a1 = __builtin_amdgcn_mfma_f32_16x16x32_bf16(kf2, qf[0], a1, 0, 0, 0);
        a1 = __builtin_amdgcn_mfma_f32_16x16x32_bf16(kf3, qf[1], a1, 0, 0, 0);

        float p0[4], p1[4];
        #pragma unroll
        for (int r = 0; r < 4; ++r) {
            p0[r] = mv0[r] ? exp2f(fmaf(a0[r], SC_L2E, -BI_L2E)) : 0.f;
            p1[r] = mv1[r] ? exp2f(fmaf(a1[r], SC_L2E, -BI_L2E)) : 0.f;
            lsum += p0[r] + p1[r];
        }
        u32x2 wa = {pk2(p0[0], p0[1]), pk2(p0[2], p0[3])};
        u32x2 wb = {pk2(p1[0], p1[1]), pk2(p1[2], p1[3])};
        *(u32x2*)&sbuf[lq * SROW + kb + 4 * lg] = wa;
        *(u32x2*)&sbuf[lq * SROW + kb + 16 + 4 * lg] = wb;
    };
    // PV for one 32-k chunk (reads p~ this wave wrote)
    auto pv = [&](int kb) {
        bf16x8 pa = *(const bf16x8*)&sbuf[lq * SROW + kb + 8 * lg];
        #pragma unroll
        for (int nt = 0; nt < 4; ++nt) {
            bf16x8 vf;
            if constexpr (PRE) {
                vf = *(const bf16x8*)(Vtb + (size_t)(nt * 16 + lq) * SN + kb + 8 * lg);
            } else {
                const float* vsrc = Vb + (size_t)(kb + 8 * lg) * DN + nt * 16 + lq;
                #pragma unroll
                for (int j = 0; j < 8; ++j) vf[j] = f2bf(vsrc[(size_t)j * DN]);
            }
            oacc[nt] = __builtin_amdgcn_mfma_f32_16x16x32_bf16(pa, vf, oacc[nt], 0, 0, 0);
        }
    };

    qkexp(k0);                                          // prologue
    for (int kb = k0 + 32; kb < k0 + KSEG; kb += 32) {  // steady state
        qkexp(kb);
        pv(kb - 32);
    }
    pv(k0 + KSEG - 32);                                 // epilogue

    // row sums: lane-local (q=lq), reduce over lg groups then waves
    lsum += __shfl_xor(lsum, 16);
    lsum += __shfl_xor(lsum, 32);
    if (lg == 0) lred[wv * QB + lq] = lsum;
    __syncthreads();
    if (tid < QB) {
        float l = 0.f;
        #pragma unroll
        for (int w = 0; w < NWAVE; ++w) l += lred[w * QB + tid];
        lfin[tid] = 1.f / l;
    }
    __syncthreads();

    // ---- store p_attn = p~/l (plain coalesced stores; 2 rows per iter) ----
    #pragma unroll 2
    for (int it = 0; it < 8; ++it) {
        const int q = 2 * it + (tid >> 8);
        const int c = (tid & 255) << 3;
        const float rl = lfin[q];
        bf16x8 s8 = *(const bf16x8*)&sbuf[q * SROW + c];
        f32x4 o0, o1;
        #pragma unroll
        for (int j = 0; j < 4; ++j) { o0[j] = bf2f(s8[j]) * rl; o1[j] = bf2f(s8[4 + j]) * rl; }
        float* dst = &out_p[(size_t)q * SN + c];
        *(f32x4*)dst = o0;
        *(f32x4*)(dst + 4) = o1;
    }
    __syncthreads();

    // ---- cross-wave O reduce (reuse sbuf), normalize, write ----
    // oacc layout: q = 4*lg+r, d = nt*16+lq
    float* obuf = (float*)sbuf;
    #pragma unroll
    for (int nt = 0; nt < 4; ++nt) {
        #pragma unroll
        for (int r = 0; r < 4; ++r)
            obuf[(wv * QB + 4 * lg + r) * DN + nt * 16 + lq] = oacc[nt][r];
    }
    __syncthreads();
    #pragma unroll
    for (int i = 0; i < 2; ++i) {
        const int idx = tid + i * 512;
        const int q = idx >> 6, d = idx & 63;
        float v = 0.f;
        #pragma unroll
        for (int w = 0; w < NWAVE; ++w) v += obuf[(w * QB + q) * DN + d];
        out_o[(size_t)q * DN + d] = v * lfin[q];
    }
}

extern "C" void kernel_launch(void* const* d_in, const int* in_sizes, int n_in,
                              void* d_out, int out_size, void* d_ws, size_t ws_size,
                              hipStream_t stream) {
    const float* Q = (const float*)d_in[0];
    const float* K = (const float*)d_in[1];
    const float* V = (const float*)d_in[2];
    const int*   M = (const int*)d_in[3];
    float* out = (float*)d_out;
    const size_t half = (size_t)BN * SN * DN;          // elements per buffer
    const size_t need = 2 * half * sizeof(short);      // 8 MB
    dim3 block(512);
    dim3 grid(BN * (SN / QB));                         // 2048 blocks
    if (ws_size >= need) {
        short* Kp = (short*)d_ws;
        short* Vt = Kp + half;
        prep_kv<<<dim3(BN * (SN / 64)), dim3(256), 0, stream>>>(K, V, Kp, Vt);
        attn_fused<1><<<grid, block, 0, stream>>>(Q, K, V, M, Kp, Vt, out);
    } else {
        attn_fused<0><<<grid, block, 0, stream>>>(Q, K, V, M, nullptr, nullptr, out);
    }
}

// Round 6
// 149.808 us; speedup vs baseline: 1.2864x; 1.2864x over previous
//
#include <hip/hip_runtime.h>
#include <hip/hip_bf16.h>

// Attention fwd with materialized p_attn.
// B=16, S=2048, D=64, f32 in/out. d_out = [out (B,S,D) | p_attn (B,S,S)] f32.
#define BN 16
#define SN 2048
#define DN 64
#define QB 16             // q rows per block
#define NWAVE 8           // 512 threads
#define KSEG (SN / NWAVE) // 256 keys per wave
#define SROW 2056         // bf16 elems per LDS score row

#define SC_L2E 0.18033688011112042f   // 0.125 * log2(e)
#define BI_L2E 11.541560327111707f    // 8 * log2(e): p~ = exp(s - 8)

typedef __attribute__((ext_vector_type(8))) short bf16x8;
typedef __attribute__((ext_vector_type(4))) short bf16x4;
typedef __attribute__((ext_vector_type(4))) float f32x4;
typedef __attribute__((ext_vector_type(4))) int   i32x4;
typedef __attribute__((ext_vector_type(2))) unsigned u32x2;

static __device__ __forceinline__ short f2bf(float f) {
    __hip_bfloat16 h = __float2bfloat16(f);
    union { __hip_bfloat16 h; short s; } u; u.h = h;
    return u.s;
}
static __device__ __forceinline__ float bf2f(short s) {
    union { unsigned u; float f; } v; v.u = ((unsigned)(unsigned short)s) << 16;
    return v.f;
}
static __device__ __forceinline__ unsigned pk2(float lo, float hi) {
    return ((unsigned)(unsigned short)f2bf(lo)) |
           (((unsigned)(unsigned short)f2bf(hi)) << 16);
}

// ---- prep: K -> bf16 [B][S][D], V -> bf16 transposed [B][D][S] (both in ws) ----
__global__ __launch_bounds__(256)
void prep_kv(const float* __restrict__ K, const float* __restrict__ V,
             short* __restrict__ Kp, short* __restrict__ Vt)
{
    __shared__ short vt[64][68];
    const int b  = blockIdx.x >> 5;
    const int s0 = (blockIdx.x & 31) << 6;
    const int tid = threadIdx.x;
    const int sr = tid >> 4;
    const int dc = (tid & 15) << 2;
    const float* Kb = K + ((size_t)b * SN + s0) * DN;
    const float* Vb = V + ((size_t)b * SN + s0) * DN;
    short* Kpb = Kp + ((size_t)b * SN + s0) * DN;
    #pragma unroll
    for (int i = 0; i < 4; ++i) {
        const int s = sr + i * 16;
        f32x4 kv = *(const f32x4*)(Kb + (size_t)s * DN + dc);
        f32x4 vv = *(const f32x4*)(Vb + (size_t)s * DN + dc);
        bf16x4 k4, v4;
        #pragma unroll
        for (int j = 0; j < 4; ++j) { k4[j] = f2bf(kv[j]); v4[j] = f2bf(vv[j]); }
        *(bf16x4*)(Kpb + (size_t)s * DN + dc) = k4;
        *(bf16x4*)&vt[s][dc] = v4;
    }
    __syncthreads();
    const int d  = tid >> 2;
    const int sg = (tid & 3) << 4;
    short* dst = Vt + ((size_t)b * DN + d) * SN + s0 + sg;
    bf16x8 w0, w1;
    #pragma unroll
    for (int j = 0; j < 8; ++j) { w0[j] = vt[sg + j][d]; w1[j] = vt[sg + 8 + j][d]; }
    *(bf16x8*)dst = w0;
    *(bf16x8*)(dst + 8) = w1;
}

// ---- fused attention: two independent passes, stores interleaved in pass B ----
// Pass A: swapped QK^T (mfma(K,Q)) -> p~=exp(s-8) -> pack -> ds_write + row sum.
//         8 fully independent iterations (no LDS reads) -> deep MLP.
// Pass B: ds_read p~ A-frag + V MFMA, with 2 rows of NT p-stores per chunk
//         (own-wave contiguous k-segment -> coalesced 16B/lane).
template <int PRE>
__global__ __launch_bounds__(512, 2)
void attn_fused(const float* __restrict__ Q, const float* __restrict__ K,
                const float* __restrict__ V, const int* __restrict__ M,
                const short* __restrict__ Kp, const short* __restrict__ Vt,
                float* __restrict__ out)
{
    __shared__ short sbuf[QB * SROW];
    __shared__ float lred[NWAVE * QB];
    __shared__ float lfin[QB];

    const int tid = threadIdx.x;
    const int wv = tid >> 6, ln = tid & 63;
    const int lq = ln & 15, lg = ln >> 4;

    // XCD-bijective swizzle (2048 blocks, 8 XCDs): XCD x gets 2 batches.
    const int lb = ((blockIdx.x & 7) << 8) | (blockIdx.x >> 3);
    const int bb = lb >> 7;
    const int q0 = (lb & 127) << 4;

    const float* Qb = Q + ((size_t)bb * SN + q0) * DN;
    const float* Kb = K + (size_t)bb * SN * DN;
    const float* Vb = V + (size_t)bb * SN * DN;
    const short* Kpb = Kp + (size_t)bb * SN * DN;
    const short* Vtb = Vt + (size_t)bb * DN * SN;
    const int*   Mb = M + (size_t)bb * SN;
    float* out_o = out + ((size_t)bb * SN + q0) * DN;
    float* out_p = out + (size_t)BN * SN * DN + ((size_t)bb * SN + q0) * SN;

    // ---- Q fragment (B-operand of swapped QK^T): Q[col=lq][d=8*lg+j] ----
    bf16x8 qf[2];
    #pragma unroll
    for (int s = 0; s < 2; ++s) {
        const float* src = Qb + lq * DN + s * 32 + lg * 8;
        f32x4 a = *(const f32x4*)src;
        f32x4 b = *(const f32x4*)(src + 4);
        #pragma unroll
        for (int j = 0; j < 4; ++j) { qf[s][j] = f2bf(a[j]); qf[s][4 + j] = f2bf(b[j]); }
    }

    const int k0 = wv * KSEG;
    float lsum = 0.f;

    // ---- pass A: QK^T + exp + pack -> LDS; row sums. Independent iters. ----
    #pragma unroll 2
    for (int kb = k0; kb < k0 + KSEG; kb += 32) {
        bf16x8 kf0, kf1, kf2, kf3;
        if constexpr (PRE) {
            const short* kr = Kpb + (size_t)(kb + lq) * DN + lg * 8;
            kf0 = *(const bf16x8*)kr;
            kf1 = *(const bf16x8*)(kr + 32);
            kf2 = *(const bf16x8*)(kr + 16 * DN);
            kf3 = *(const bf16x8*)(kr + 16 * DN + 32);
        } else {
            const float* ks = Kb + (size_t)(kb + lq) * DN + lg * 8;
            #pragma unroll
            for (int j = 0; j < 8; ++j) {
                kf0[j] = f2bf(ks[j]);            kf1[j] = f2bf(ks[32 + j]);
                kf2[j] = f2bf(ks[16 * DN + j]);  kf3[j] = f2bf(ks[16 * DN + 32 + j]);
            }
        }
        const i32x4 mv0 = *(const i32x4*)&Mb[kb + 4 * lg];
        const i32x4 mv1 = *(const i32x4*)&Mb[kb + 16 + 4 * lg];

        f32x4 a0 = {0.f, 0.f, 0.f, 0.f}, a1 = {0.f, 0.f, 0.f, 0.f};
        a0 = __builtin_amdgcn_mfma_f32_16x16x32_bf16(kf0, qf[0], a0, 0, 0, 0);
        a0 = __builtin_amdgcn_mfma_f32_16x16x32_bf16(kf1, qf[1], a0, 0, 0, 0);
        a1 = __builtin_amdgcn_mfma_f32_16x16x32_bf16(kf2, qf[0], a1, 0, 0, 0);
        a1 = __builtin_amdgcn_mfma_f32_16x16x32_bf16(kf3, qf[1], a1, 0, 0, 0);

        float p0[4], p1[4];
        #pragma unroll
        for (int r = 0; r < 4; ++r) {
            p0[r] = mv0[r] ? exp2f(fmaf(a0[r], SC_L2E, -BI_L2E)) : 0.f;
            p1[r] = mv1[r] ? exp2f(fmaf(a1[r], SC_L2E, -BI_L2E)) : 0.f;
            lsum += p0[r] + p1[r];
        }
        u32x2 wa = {pk2(p0[0], p0[1]), pk2(p0[2], p0[3])};
        u32x2 wb = {pk2(p1[0], p1[1]), pk2(p1[2], p1[3])};
        *(u32x2*)&sbuf[lq * SROW + kb + 4 * lg] = wa;
        *(u32x2*)&sbuf[lq * SROW + kb + 16 + 4 * lg] = wb;
    }

    // row sums: lane-local (q=lq), reduce over lg then waves
    lsum += __shfl_xor(lsum, 16);
    lsum += __shfl_xor(lsum, 32);
    if (lg == 0) lred[wv * QB + lq] = lsum;
    __syncthreads();
    if (tid < QB) {
        float l = 0.f;
        #pragma unroll
        for (int w = 0; w < NWAVE; ++w) l += lred[w * QB + tid];
        lfin[tid] = 1.f / l;
    }
    __syncthreads();

    // ---- pass B: PV MFMA + interleaved NT p-stores (2 rows per chunk) ----
    f32x4 oacc[4];
    #pragma unroll
    for (int nt = 0; nt < 4; ++nt) oacc[nt] = (f32x4){0.f, 0.f, 0.f, 0.f};

    #pragma unroll 2
    for (int c = 0; c < KSEG / 32; ++c) {
        const int kb = k0 + c * 32;
        bf16x8 pa = *(const bf16x8*)&sbuf[lq * SROW + kb + 8 * lg];
        #pragma unroll
        for (int nt = 0; nt < 4; ++nt) {
            bf16x8 vf;
            if constexpr (PRE) {
                vf = *(const bf16x8*)(Vtb + (size_t)(nt * 16 + lq) * SN + kb + 8 * lg);
            } else {
                const float* vsrc = Vb + (size_t)(kb + 8 * lg) * DN + nt * 16 + lq;
                #pragma unroll
                for (int j = 0; j < 8; ++j) vf[j] = f2bf(vsrc[(size_t)j * DN]);
            }
            oacc[nt] = __builtin_amdgcn_mfma_f32_16x16x32_bf16(pa, vf, oacc[nt], 0, 0, 0);
        }
        // store 2 q-rows of this wave's k-segment: contiguous 1 KB, 16B/lane
        #pragma unroll
        for (int j = 0; j < 2; ++j) {
            const int q = 2 * c + j;
            const float rl = lfin[q];
            bf16x4 s4 = *(const bf16x4*)&sbuf[q * SROW + k0 + ln * 4];
            f32x4 o;
            o[0] = bf2f(s4[0]) * rl; o[1] = bf2f(s4[1]) * rl;
            o[2] = bf2f(s4[2]) * rl; o[3] = bf2f(s4[3]) * rl;
            __builtin_nontemporal_store(o, (f32x4*)&out_p[(size_t)q * SN + k0 + ln * 4]);
        }
    }
    __syncthreads();

    // ---- cross-wave O reduce (reuse sbuf), normalize, write ----
    // oacc layout: q = 4*lg+r, d = nt*16+lq
    float* obuf = (float*)sbuf;
    #pragma unroll
    for (int nt = 0; nt < 4; ++nt) {
        #pragma unroll
        for (int r = 0; r < 4; ++r)
            obuf[(wv * QB + 4 * lg + r) * DN + nt * 16 + lq] = oacc[nt][r];
    }
    __syncthreads();
    #pragma unroll
    for (int i = 0; i < 2; ++i) {
        const int idx = tid + i * 512;
        const int q = idx >> 6, d = idx & 63;
        float v = 0.f;
        #pragma unroll
        for (int w = 0; w < NWAVE; ++w) v += obuf[(w * QB + q) * DN + d];
        out_o[(size_t)q * DN + d] = v * lfin[q];
    }
}

extern "C" void kernel_launch(void* const* d_in, const int* in_sizes, int n_in,
                              void* d_out, int out_size, void* d_ws, size_t ws_size,
                              hipStream_t stream) {
    const float* Q = (const float*)d_in[0];
    const float* K = (const float*)d_in[1];
    const float* V = (const float*)d_in[2];
    const int*   M = (const int*)d_in[3];
    float* out = (float*)d_out;
    const size_t half = (size_t)BN * SN * DN;
    const size_t need = 2 * half * sizeof(short);      // 8 MB
    dim3 block(512);
    dim3 grid(BN * (SN / QB));                         // 2048 blocks
    if (ws_size >= need) {
        short* Kp = (short*)d_ws;
        short* Vt = Kp + half;
        prep_kv<<<dim3(BN * (SN / 64)), dim3(256), 0, stream>>>(K, V, Kp, Vt);
        attn_fused<1><<<grid, block, 0, stream>>>(Q, K, V, M, Kp, Vt, out);
    } else {
        attn_fused<0><<<grid, block, 0, stream>>>(Q, K, V, M, nullptr, nullptr, out);
    }
}